// Round 1
// baseline (2363.770 us; speedup 1.0000x reference)
//
#include <hip/hip_runtime.h>
#include <hip/hip_bf16.h>

#define G 64
#define NVOX (G*G*G)
#define INC 32
#define OUTC 64

// ---------------------------------------------------------------------------
// Stage 1: scatter-mean accumulation. 8 threads per point, 4 channels each.
// ---------------------------------------------------------------------------
__global__ __launch_bounds__(256) void scatter_kernel(
    const float* __restrict__ pts, const float* __restrict__ feats,
    float* __restrict__ sums, float* __restrict__ cnts, int npts)
{
    int tid = blockIdx.x * 256 + threadIdx.x;
    int p = tid >> 3;
    int q = tid & 7;
    if (p >= npts) return;

    float px = pts[p * 3 + 0];
    float py = pts[p * 3 + 1];
    float pz = pts[p * 3 + 2];
    int bx = (int)floorf(px);
    int by = (int)floorf(py);
    int bz = (int)floorf(pz);
    bx = min(max(bx, 0), G - 1);
    by = min(max(by, 0), G - 1);
    bz = min(max(bz, 0), G - 1);
    int fl = (bx * G + by) * G + bz;

    float4 f = ((const float4*)feats)[p * 8 + q];
    float* dst = sums + (size_t)fl * INC + q * 4;
    atomicAdd(dst + 0, f.x);
    atomicAdd(dst + 1, f.y);
    atomicAdd(dst + 2, f.z);
    atomicAdd(dst + 3, f.w);
    if (q == 0) atomicAdd(cnts + fl, 1.0f);
}

// ---------------------------------------------------------------------------
// Stage 2: sums -> means (in place). One thread per float4 (8 per voxel).
// ---------------------------------------------------------------------------
__global__ __launch_bounds__(256) void normalize_kernel(
    float* __restrict__ sums, const float* __restrict__ cnts)
{
    int t = blockIdx.x * 256 + threadIdx.x;   // over NVOX*8 float4s
    int v = t >> 3;
    float c = cnts[v];
    float inv = 1.0f / fmaxf(c, 1.0f);
    float4* s4 = (float4*)sums;
    float4 a = s4[t];
    a.x *= inv; a.y *= inv; a.z *= inv; a.w *= inv;
    s4[t] = a;
}

// ---------------------------------------------------------------------------
// Stage 3: dense 3x3x3 conv, 32 -> 64 channels, SAME padding.
// One thread per voxel, 64 fp32 accumulators. W indices are wave-uniform so
// the compiler scalarizes W reads (s_load + SGPR operand on v_fmac_f32).
// ---------------------------------------------------------------------------
__global__ __launch_bounds__(256) void conv_kernel(
    const float* __restrict__ voxf, const float* __restrict__ Wc,
    float* __restrict__ convo)
{
    int v = blockIdx.x * 256 + threadIdx.x;
    int z = v & (G - 1);
    int y = (v >> 6) & (G - 1);
    int x = v >> 12;

    float acc[OUTC];
#pragma unroll
    for (int n = 0; n < OUTC; n++) acc[n] = 0.0f;

#pragma unroll 1
    for (int off = 0; off < 27; off++) {
        int dx = off / 9 - 1;
        int dy = (off / 3) % 3 - 1;
        int dz = off % 3 - 1;
        int nx = x + dx, ny = y + dy, nz = z + dz;
        if ((unsigned)nx >= (unsigned)G || (unsigned)ny >= (unsigned)G ||
            (unsigned)nz >= (unsigned)G)
            continue;
        int nb = v + dx * (G * G) + dy * G + dz;
        const float4* in4 = (const float4*)(voxf + (size_t)nb * INC);
        const float* Wo = Wc + off * (INC * OUTC);
#pragma unroll 1
        for (int k4 = 0; k4 < 8; k4++) {
            float4 f = in4[k4];
            const float* wr0 = Wo + (k4 * 4 + 0) * OUTC;
            const float* wr1 = Wo + (k4 * 4 + 1) * OUTC;
            const float* wr2 = Wo + (k4 * 4 + 2) * OUTC;
            const float* wr3 = Wo + (k4 * 4 + 3) * OUTC;
#pragma unroll
            for (int n = 0; n < OUTC; n++) {
                acc[n] += f.x * wr0[n];
                acc[n] += f.y * wr1[n];
                acc[n] += f.z * wr2[n];
                acc[n] += f.w * wr3[n];
            }
        }
    }

    float4* o4 = (float4*)(convo + (size_t)v * OUTC);
#pragma unroll
    for (int n = 0; n < OUTC / 4; n++)
        o4[n] = make_float4(acc[4 * n], acc[4 * n + 1], acc[4 * n + 2], acc[4 * n + 3]);
}

// ---------------------------------------------------------------------------
// Stage 4: trilinear devoxelize + residual linear. One WAVE per point,
// lane = output channel (all per-point scalars are wave-uniform).
// Block 256 = 4 waves = 4 points.
// ---------------------------------------------------------------------------
__global__ __launch_bounds__(256) void gather_kernel(
    const float* __restrict__ pts, const float* __restrict__ feats,
    const float* __restrict__ convo, const float* __restrict__ cnts,
    const float* __restrict__ Wl, const float* __restrict__ bl,
    float* __restrict__ out, int npts)
{
    __shared__ float sW[INC * OUTC];   // transposed: sW[k*64 + c]
    for (int i = threadIdx.x; i < INC * OUTC; i += 256) {
        int c = i >> 5;        // Wl layout [c][k], c in [0,64)
        int k = i & 31;
        sW[k * OUTC + c] = Wl[i];
    }
    __syncthreads();

    int p = blockIdx.x * 4 + (threadIdx.x >> 6);
    int c = threadIdx.x & 63;
    if (p >= npts) return;

    float px = pts[p * 3 + 0];
    float py = pts[p * 3 + 1];
    float pz = pts[p * 3 + 2];
    int bx = (int)floorf(px);
    int by = (int)floorf(py);
    int bz = (int)floorf(pz);
    float fx = px - (float)bx;
    float fy = py - (float)by;
    float fz = pz - (float)bz;

    float acc = bl[c];

    // residual linear: feats[p] @ Wl^T
    const float* fr = feats + (size_t)p * INC;
#pragma unroll
    for (int k = 0; k < INC; k++)
        acc += fr[k] * sW[k * OUTC + c];

    // 8-corner trilinear gather
#pragma unroll
    for (int corner = 0; corner < 8; corner++) {
        int dx = (corner >> 2) & 1;
        int dy = (corner >> 1) & 1;
        int dz = corner & 1;
        int nx = bx + dx, ny = by + dy, nz = bz + dz;
        bool inb = ((unsigned)nx < (unsigned)G) && ((unsigned)ny < (unsigned)G) &&
                   ((unsigned)nz < (unsigned)G);
        int cx = min(max(nx, 0), G - 1);
        int cy = min(max(ny, 0), G - 1);
        int cz = min(max(nz, 0), G - 1);
        int fl = (cx * G + cy) * G + cz;
        float w = (dx ? fx : 1.0f - fx) * (dy ? fy : 1.0f - fy) * (dz ? fz : 1.0f - fz);
        if (!inb || !(cnts[fl] > 0.0f)) w = 0.0f;
        acc += w * convo[(size_t)fl * OUTC + c];
    }

    out[(size_t)p * OUTC + c] = acc;
}

// ---------------------------------------------------------------------------
extern "C" void kernel_launch(void* const* d_in, const int* in_sizes, int n_in,
                              void* d_out, int out_size, void* d_ws, size_t ws_size,
                              hipStream_t stream)
{
    const float* pts   = (const float*)d_in[0];
    const float* feats = (const float*)d_in[1];
    const float* Wc    = (const float*)d_in[2];
    const float* Wl    = (const float*)d_in[3];
    const float* bl    = (const float*)d_in[4];
    float* out = (float*)d_out;
    int npts = in_sizes[0] / 3;

    // workspace layout
    float* sums  = (float*)d_ws;                    // NVOX*32
    float* cnts  = sums + (size_t)NVOX * INC;       // NVOX
    float* convo = cnts + NVOX;                     // NVOX*64

    // zero scatter accumulators (sums + cnts = NVOX*33 floats)
    hipMemsetAsync(d_ws, 0, (size_t)NVOX * (INC + 1) * sizeof(float), stream);

    int scatter_blocks = (npts * 8 + 255) / 256;
    scatter_kernel<<<scatter_blocks, 256, 0, stream>>>(pts, feats, sums, cnts, npts);

    normalize_kernel<<<(NVOX * 8) / 256, 256, 0, stream>>>(sums, cnts);

    conv_kernel<<<NVOX / 256, 256, 0, stream>>>(sums, Wc, convo);

    gather_kernel<<<(npts + 3) / 4, 256, 0, stream>>>(pts, feats, convo, cnts,
                                                      Wl, bl, out, npts);
}

// Round 2
// 2047.655 us; speedup vs baseline: 1.1544x; 1.1544x over previous
//
#include <hip/hip_runtime.h>
#include <hip/hip_bf16.h>

#define G 64
#define NVOX (G*G*G)
#define INC 32
#define OUTC 64

// ---------------------------------------------------------------------------
// Stage 1: scatter-mean accumulation. 8 threads per point, 4 channels each.
// ---------------------------------------------------------------------------
__global__ __launch_bounds__(256) void scatter_kernel(
    const float* __restrict__ pts, const float* __restrict__ feats,
    float* __restrict__ sums, float* __restrict__ cnts, int npts)
{
    int tid = blockIdx.x * 256 + threadIdx.x;
    int p = tid >> 3;
    int q = tid & 7;
    if (p >= npts) return;

    float px = pts[p * 3 + 0];
    float py = pts[p * 3 + 1];
    float pz = pts[p * 3 + 2];
    int bx = (int)floorf(px);
    int by = (int)floorf(py);
    int bz = (int)floorf(pz);
    bx = min(max(bx, 0), G - 1);
    by = min(max(by, 0), G - 1);
    bz = min(max(bz, 0), G - 1);
    int fl = (bx * G + by) * G + bz;

    float4 f = ((const float4*)feats)[p * 8 + q];
    float* dst = sums + (size_t)fl * INC + q * 4;
    atomicAdd(dst + 0, f.x);
    atomicAdd(dst + 1, f.y);
    atomicAdd(dst + 2, f.z);
    atomicAdd(dst + 3, f.w);
    if (q == 0) atomicAdd(cnts + fl, 1.0f);
}

// ---------------------------------------------------------------------------
// Stage 2: sums -> means (in place). One thread per float4 (8 per voxel).
// ---------------------------------------------------------------------------
__global__ __launch_bounds__(256) void normalize_kernel(
    float* __restrict__ sums, const float* __restrict__ cnts)
{
    int t = blockIdx.x * 256 + threadIdx.x;   // over NVOX*8 float4s
    int v = t >> 3;
    float c = cnts[v];
    float inv = 1.0f / fmaxf(c, 1.0f);
    float4* s4 = (float4*)sums;
    float4 a = s4[t];
    a.x *= inv; a.y *= inv; a.z *= inv; a.w *= inv;
    s4[t] = a;
}

// ---------------------------------------------------------------------------
// Stage 3: dense 3x3x3 conv, 32 -> 64 channels, SAME padding.
// One thread per voxel, 64 fp32 accumulators; W reads are wave-uniform
// (scalarized to s_load by the compiler).
// ---------------------------------------------------------------------------
__global__ __launch_bounds__(256) void conv_kernel(
    const float* __restrict__ voxf, const float* __restrict__ Wc,
    float* __restrict__ convo)
{
    int v = blockIdx.x * 256 + threadIdx.x;
    int z = v & (G - 1);
    int y = (v >> 6) & (G - 1);
    int x = v >> 12;

    float acc[OUTC];
#pragma unroll
    for (int n = 0; n < OUTC; n++) acc[n] = 0.0f;

#pragma unroll 1
    for (int off = 0; off < 27; off++) {
        int dx = off / 9 - 1;
        int dy = (off / 3) % 3 - 1;
        int dz = off % 3 - 1;
        int nx = x + dx, ny = y + dy, nz = z + dz;
        if ((unsigned)nx >= (unsigned)G || (unsigned)ny >= (unsigned)G ||
            (unsigned)nz >= (unsigned)G)
            continue;
        int nb = v + dx * (G * G) + dy * G + dz;
        const float4* in4 = (const float4*)(voxf + (size_t)nb * INC);
        const float* Wo = Wc + off * (INC * OUTC);
#pragma unroll 1
        for (int k4 = 0; k4 < 8; k4++) {
            float4 f = in4[k4];
            const float* wr0 = Wo + (k4 * 4 + 0) * OUTC;
            const float* wr1 = Wo + (k4 * 4 + 1) * OUTC;
            const float* wr2 = Wo + (k4 * 4 + 2) * OUTC;
            const float* wr3 = Wo + (k4 * 4 + 3) * OUTC;
#pragma unroll
            for (int n = 0; n < OUTC; n++) {
                acc[n] += f.x * wr0[n];
                acc[n] += f.y * wr1[n];
                acc[n] += f.z * wr2[n];
                acc[n] += f.w * wr3[n];
            }
        }
    }

    float4* o4 = (float4*)(convo + (size_t)v * OUTC);
#pragma unroll
    for (int n = 0; n < OUTC / 4; n++)
        o4[n] = make_float4(acc[4 * n], acc[4 * n + 1], acc[4 * n + 2], acc[4 * n + 3]);
}

// ---------------------------------------------------------------------------
// Stage 4: trilinear devoxelize + residual linear. One WAVE per point,
// lane = output channel. LDS weight tile padded to stride 65 floats:
// store banks (k+c)%32 conflict-free, reads 2-way (free).
// ---------------------------------------------------------------------------
#define WPAD 65

__global__ __launch_bounds__(256) void gather_kernel(
    const float* __restrict__ pts, const float* __restrict__ feats,
    const float* __restrict__ convo, const float* __restrict__ cnts,
    const float* __restrict__ Wl, const float* __restrict__ bl,
    float* __restrict__ out, int npts)
{
    __shared__ float sW[INC * WPAD];   // sW[k*WPAD + c], c in [0,64)
    for (int i = threadIdx.x; i < INC * OUTC; i += 256) {
        int c = i >> 5;        // Wl layout [c][k]
        int k = i & 31;
        sW[k * WPAD + c] = Wl[i];
    }
    __syncthreads();

    int p = blockIdx.x * 4 + (threadIdx.x >> 6);
    int c = threadIdx.x & 63;
    if (p >= npts) return;

    float px = pts[p * 3 + 0];
    float py = pts[p * 3 + 1];
    float pz = pts[p * 3 + 2];
    int bx = (int)floorf(px);
    int by = (int)floorf(py);
    int bz = (int)floorf(pz);
    float fx = px - (float)bx;
    float fy = py - (float)by;
    float fz = pz - (float)bz;

    // ---- issue all 8 corner gathers first (independent loads, overlap VALU)
    float cw[8];
    float cv[8];
#pragma unroll
    for (int corner = 0; corner < 8; corner++) {
        int dx = (corner >> 2) & 1;
        int dy = (corner >> 1) & 1;
        int dz = corner & 1;
        int nx = bx + dx, ny = by + dy, nz = bz + dz;
        bool inb = ((unsigned)nx < (unsigned)G) && ((unsigned)ny < (unsigned)G) &&
                   ((unsigned)nz < (unsigned)G);
        int cx = min(max(nx, 0), G - 1);
        int cy = min(max(ny, 0), G - 1);
        int cz = min(max(nz, 0), G - 1);
        int fl = (cx * G + cy) * G + cz;
        float w = (dx ? fx : 1.0f - fx) * (dy ? fy : 1.0f - fy) * (dz ? fz : 1.0f - fz);
        if (!inb || !(cnts[fl] > 0.0f)) w = 0.0f;
        cw[corner] = w;
        cv[corner] = convo[(size_t)fl * OUTC + c];
    }

    float acc = bl[c];

    // residual linear: feats[p] @ Wl^T
    const float* fr = feats + (size_t)p * INC;
#pragma unroll
    for (int k = 0; k < INC; k++)
        acc += fr[k] * sW[k * WPAD + c];

#pragma unroll
    for (int corner = 0; corner < 8; corner++)
        acc += cw[corner] * cv[corner];

    out[(size_t)p * OUTC + c] = acc;
}

// ---------------------------------------------------------------------------
extern "C" void kernel_launch(void* const* d_in, const int* in_sizes, int n_in,
                              void* d_out, int out_size, void* d_ws, size_t ws_size,
                              hipStream_t stream)
{
    const float* pts   = (const float*)d_in[0];
    const float* feats = (const float*)d_in[1];
    const float* Wc    = (const float*)d_in[2];
    const float* Wl    = (const float*)d_in[3];
    const float* bl    = (const float*)d_in[4];
    float* out = (float*)d_out;
    int npts = in_sizes[0] / 3;

    // workspace layout
    float* sums  = (float*)d_ws;                    // NVOX*32
    float* cnts  = sums + (size_t)NVOX * INC;       // NVOX
    float* convo = cnts + NVOX;                     // NVOX*64

    // zero scatter accumulators (sums + cnts = NVOX*33 floats)
    hipMemsetAsync(d_ws, 0, (size_t)NVOX * (INC + 1) * sizeof(float), stream);

    int scatter_blocks = (npts * 8 + 255) / 256;
    scatter_kernel<<<scatter_blocks, 256, 0, stream>>>(pts, feats, sums, cnts, npts);

    normalize_kernel<<<(NVOX * 8) / 256, 256, 0, stream>>>(sums, cnts);

    conv_kernel<<<NVOX / 256, 256, 0, stream>>>(sums, Wc, convo);

    gather_kernel<<<(npts + 3) / 4, 256, 0, stream>>>(pts, feats, convo, cnts,
                                                      Wl, bl, out, npts);
}